// Round 1
// baseline (613.743 us; speedup 1.0000x reference)
//
#include <hip/hip_runtime.h>
#include <math.h>

// ---------------------------------------------------------------------------
// GATv2 x2 layers, N=50000, D=128, HID=128, heads 4 then 1, E=800000 (+ self loops)
// Plan:
//   1) CSR build by dst (hist -> scan -> scatter), reused by both layers
//   2) dual GEMM (fp32 vector): xl = X@Wl, xr = X@Wr  (fused, read X once)
//   3) edge aggregation: one wave per dst node, online softmax, no atomics
// ---------------------------------------------------------------------------

#define NEG_SLOPE 0.2f

// ---------------- CSR build --------------------------------------------------

__global__ __launch_bounds__(256)
void hist_kernel(const int* __restrict__ dstA, int* __restrict__ deg, int E, int Et) {
    int e = blockIdx.x * blockDim.x + threadIdx.x;
    if (e >= Et) return;
    int d = (e < E) ? dstA[e] : (e - E);   // self loops appended after edges
    atomicAdd(&deg[d], 1);
}

// single-block exclusive scan producing rowptr[0..n]
__global__ __launch_bounds__(1024)
void scan_block(const int* __restrict__ deg, int* __restrict__ rowptr, int n) {
    __shared__ int wsum[16];
    int t = threadIdx.x;
    int lane = t & 63, wid = t >> 6;
    int carry = 0;
    if (t == 0) rowptr[0] = 0;
    for (int base = 0; base < n; base += 1024) {
        int i = base + t;
        int v = (i < n) ? deg[i] : 0;
        int x = v;
        #pragma unroll
        for (int off = 1; off < 64; off <<= 1) {
            int y = __shfl_up(x, off, 64);
            if (lane >= off) x += y;
        }
        if (lane == 63) wsum[wid] = x;
        __syncthreads();
        if (wid == 0) {
            int s = (lane < 16) ? wsum[lane] : 0;
            #pragma unroll
            for (int off = 1; off < 16; off <<= 1) {
                int y = __shfl_up(s, off, 64);
                if (lane >= off) s += y;
            }
            if (lane < 16) wsum[lane] = s;
        }
        __syncthreads();
        int woff = (wid == 0) ? 0 : wsum[wid - 1];
        if (i < n) rowptr[i + 1] = carry + woff + x;
        carry += wsum[15];
        __syncthreads();
    }
}

__global__ __launch_bounds__(256)
void scatter_kernel(const int* __restrict__ srcA, const int* __restrict__ dstA,
                    const int* __restrict__ rowptr, int* __restrict__ cnt,
                    int* __restrict__ srcs, int E, int Et) {
    int e = blockIdx.x * blockDim.x + threadIdx.x;
    if (e >= Et) return;
    int s, d;
    if (e < E) { s = srcA[e]; d = dstA[e]; } else { s = e - E; d = s; }
    int pos = rowptr[d] + atomicAdd(&cnt[d], 1);
    srcs[pos] = s;
}

// ---------------- dual GEMM: outL = X@Wl, outR = X@Wr (all [*,128]x[128,128])

__global__ __launch_bounds__(256)
void gemm_dual(const float* __restrict__ X, const float* __restrict__ Wl,
               const float* __restrict__ Wr, float* __restrict__ outL,
               float* __restrict__ outR, int n) {
    __shared__ float sX[16][64];    // [k][row]  (transposed X tile)
    __shared__ float sW[16][256];   // [k][col]  cols 0-127 Wl, 128-255 Wr
    int tid  = threadIdx.x;
    int row0 = blockIdx.x * 64;
    int rowg = tid >> 5;            // 0..7  -> rows rowg*8..+7
    int colg = tid & 31;            // 0..31 -> cols colg*8..+7
    // staging indices
    int lrow = tid >> 2;            // 0..63
    int lk   = (tid & 3) * 4;       // 0,4,8,12
    int wc   = (tid & 63) * 4;      // 0..252
    int wk   = tid >> 6;            // 0..3

    float acc[8][8] = {};

    for (int kt = 0; kt < 128; kt += 16) {
        int grow = row0 + lrow;
        float4 xv = make_float4(0.f, 0.f, 0.f, 0.f);
        if (grow < n) xv = *(const float4*)(X + (size_t)grow * 128 + kt + lk);
        sX[lk + 0][lrow] = xv.x; sX[lk + 1][lrow] = xv.y;
        sX[lk + 2][lrow] = xv.z; sX[lk + 3][lrow] = xv.w;
        #pragma unroll
        for (int i = 0; i < 4; ++i) {
            int k = wk + i * 4;
            const float* Wsrc = (wc < 128)
                ? (Wl + (size_t)(kt + k) * 128 + wc)
                : (Wr + (size_t)(kt + k) * 128 + (wc - 128));
            *(float4*)(&sW[k][wc]) = *(const float4*)Wsrc;
        }
        __syncthreads();
        #pragma unroll
        for (int k = 0; k < 16; ++k) {
            float xr_[8], wv[8];
            *(float4*)&xr_[0] = *(const float4*)&sX[k][rowg * 8];
            *(float4*)&xr_[4] = *(const float4*)&sX[k][rowg * 8 + 4];
            *(float4*)&wv[0]  = *(const float4*)&sW[k][colg * 8];
            *(float4*)&wv[4]  = *(const float4*)&sW[k][colg * 8 + 4];
            #pragma unroll
            for (int r = 0; r < 8; ++r)
                #pragma unroll
                for (int c = 0; c < 8; ++c)
                    acc[r][c] += xr_[r] * wv[c];
        }
        __syncthreads();
    }
    #pragma unroll
    for (int r = 0; r < 8; ++r) {
        int grow = row0 + rowg * 8 + r;
        if (grow >= n) break;
        float* dst = (colg < 16) ? (outL + (size_t)grow * 128 + colg * 8)
                                 : (outR + (size_t)grow * 128 + (colg - 16) * 8);
        *(float4*)(dst)     = *(float4*)&acc[r][0];
        *(float4*)(dst + 4) = *(float4*)&acc[r][4];
    }
}

// ---------------- edge aggregation: one wave per dst node, online softmax ----
// GROUP = lanes per head group (16 for H=4/C=32, 64 for H=1/C=128)

template <int GROUP>
__global__ __launch_bounds__(256)
void edge_aggregate(const float* __restrict__ xl, const float* __restrict__ xr,
                    const float* __restrict__ att, const float* __restrict__ bias,
                    const int* __restrict__ rowptr, const int* __restrict__ srcs,
                    float* __restrict__ out, int n, int relu_out) {
    int wave = blockIdx.x * (blockDim.x >> 6) + (threadIdx.x >> 6);
    int lane = threadIdx.x & 63;
    if (wave >= n) return;
    int i  = wave;
    int ch = lane * 2;

    float2 xrv  = *(const float2*)(xr + (size_t)i * 128 + ch);
    float2 attv = *(const float2*)(att + ch);

    float  m = -INFINITY, l = 0.f;
    float2 acc = make_float2(0.f, 0.f);

    int jb = rowptr[i], je = rowptr[i + 1];
    for (int j = jb; j < je; ++j) {
        int s = srcs[j];
        float2 xlv = *(const float2*)(xl + (size_t)s * 128 + ch);
        float ex = xlv.x + xrv.x; ex = (ex > 0.f) ? ex : NEG_SLOPE * ex;
        float ey = xlv.y + xrv.y; ey = (ey > 0.f) ? ey : NEG_SLOPE * ey;
        float p = ex * attv.x + ey * attv.y;
        #pragma unroll
        for (int off = 1; off < GROUP; off <<= 1) p += __shfl_xor(p, off, 64);
        float mn = fmaxf(m, p);
        float sc = __expf(m - mn);   // exp(-inf)=0 on first edge
        float pe = __expf(p - mn);
        acc.x = acc.x * sc + pe * xlv.x;
        acc.y = acc.y * sc + pe * xlv.y;
        l = l * sc + pe;
        m = mn;
    }
    float inv = 1.0f / l;            // every node has a self loop -> l > 0
    float2 bv = *(const float2*)(bias + ch);
    float ox = acc.x * inv + bv.x;
    float oy = acc.y * inv + bv.y;
    if (relu_out) { ox = fmaxf(ox, 0.f); oy = fmaxf(oy, 0.f); }
    *(float2*)(out + (size_t)i * 128 + ch) = make_float2(ox, oy);
}

// ---------------- launch -----------------------------------------------------

extern "C" void kernel_launch(void* const* d_in, const int* in_sizes, int n_in,
                              void* d_out, int out_size, void* d_ws, size_t ws_size,
                              hipStream_t stream) {
    const float* x    = (const float*)d_in[0];
    const int*   ei   = (const int*)d_in[1];   // [2,E] int32
    const float* Wl1  = (const float*)d_in[2];
    const float* Wr1  = (const float*)d_in[3];
    const float* att1 = (const float*)d_in[4]; // [4,32] -> flat 128
    const float* b1   = (const float*)d_in[5];
    const float* Wl2  = (const float*)d_in[6];
    const float* Wr2  = (const float*)d_in[7];
    const float* att2 = (const float*)d_in[8]; // [1,128]
    const float* b2   = (const float*)d_in[9];

    int n  = in_sizes[0] / 128;
    int E  = in_sizes[1] / 2;
    int Et = E + n;                  // with self loops

    float* ws = (float*)d_ws;
    float* xl = ws;                              // [n,128]
    float* xr = xl + (size_t)n * 128;            // [n,128]
    float* h  = xr + (size_t)n * 128;            // [n,128]
    int* rowptr = (int*)(h + (size_t)n * 128);   // [n+1]
    int* cnt    = rowptr + (n + 1);              // [n] (also deg histogram)
    int* srcs   = cnt + n;                       // [Et]

    const int* srcA = ei;
    const int* dstA = ei + E;

    // CSR build (reused by both layers)
    hipMemsetAsync(cnt, 0, (size_t)n * 4, stream);
    hist_kernel<<<(Et + 255) / 256, 256, 0, stream>>>(dstA, cnt, E, Et);
    scan_block<<<1, 1024, 0, stream>>>(cnt, rowptr, n);
    hipMemsetAsync(cnt, 0, (size_t)n * 4, stream);
    scatter_kernel<<<(Et + 255) / 256, 256, 0, stream>>>(srcA, dstA, rowptr, cnt, srcs, E, Et);

    int gemm_grid = (n + 63) / 64;
    int edge_grid = (n + 3) / 4;

    // layer 1 (H=4, C=32): h = relu(aggregate + b1)
    gemm_dual<<<gemm_grid, 256, 0, stream>>>(x, Wl1, Wr1, xl, xr, n);
    edge_aggregate<16><<<edge_grid, 256, 0, stream>>>(xl, xr, att1, b1, rowptr, srcs, h, n, 1);

    // layer 2 (H=1, C=128): out = aggregate + b2
    gemm_dual<<<gemm_grid, 256, 0, stream>>>(h, Wl2, Wr2, xl, xr, n);
    edge_aggregate<64><<<edge_grid, 256, 0, stream>>>(xl, xr, att2, b2, rowptr, srcs, (float*)d_out, n, 0);
}

// Round 2
// 470.412 us; speedup vs baseline: 1.3047x; 1.3047x over previous
//
#include <hip/hip_runtime.h>
#include <hip/hip_fp16.h>
#include <math.h>

// ---------------------------------------------------------------------------
// GATv2 x2 layers, N=50000, D=128, HID=128, heads 4 then 1, E=800000 (+ self loops)
//   1) CSR build by dst (hist -> vectorized scan -> scatter), reused by both layers
//   2) dual GEMM (fp32 vector math): xl(fp16) = X@Wl, xr(fp32) = X@Wr
//   3) edge aggregation: one wave per dst node, online softmax, fp16 gathers,
//      4-edge ILP unroll, no float atomics
// ---------------------------------------------------------------------------

#define NEG_SLOPE 0.2f

// ---------------- CSR build --------------------------------------------------

__global__ __launch_bounds__(256)
void hist_kernel(const int* __restrict__ dstA, int* __restrict__ deg, int E, int Et) {
    int e = blockIdx.x * blockDim.x + threadIdx.x;
    if (e >= Et) return;
    int d = (e < E) ? dstA[e] : (e - E);   // self loops appended after edges
    atomicAdd(&deg[d], 1);
}

// single-block exclusive scan producing rowptr[0..n], 4 elements/thread/iter
__global__ __launch_bounds__(1024)
void scan_block(const int* __restrict__ deg, int* __restrict__ rowptr, int n) {
    __shared__ int wsum[16];
    int t = threadIdx.x;
    int lane = t & 63, wid = t >> 6;
    int carry = 0;
    if (t == 0) rowptr[0] = 0;
    for (int base = 0; base < n; base += 4096) {
        int i0 = base + t * 4;
        int v0 = 0, v1 = 0, v2 = 0, v3 = 0;
        if (i0 + 3 < n) {
            int4 q = *(const int4*)(deg + i0);
            v0 = q.x; v1 = q.y; v2 = q.z; v3 = q.w;
        } else {
            if (i0 + 0 < n) v0 = deg[i0 + 0];
            if (i0 + 1 < n) v1 = deg[i0 + 1];
            if (i0 + 2 < n) v2 = deg[i0 + 2];
            if (i0 + 3 < n) v3 = deg[i0 + 3];
        }
        int s1 = v0 + v1, s2 = s1 + v2, s3 = s2 + v3;
        int x = s3;
        #pragma unroll
        for (int off = 1; off < 64; off <<= 1) {
            int y = __shfl_up(x, off, 64);
            if (lane >= off) x += y;
        }
        if (lane == 63) wsum[wid] = x;
        __syncthreads();
        if (wid == 0) {
            int s = (lane < 16) ? wsum[lane] : 0;
            #pragma unroll
            for (int off = 1; off < 16; off <<= 1) {
                int y = __shfl_up(s, off, 64);
                if (lane >= off) s += y;
            }
            if (lane < 16) wsum[lane] = s;
        }
        __syncthreads();
        int woff = (wid == 0) ? 0 : wsum[wid - 1];
        int excl = carry + woff + x - s3;      // exclusive prefix of this thread's 4
        if (i0 + 0 < n) rowptr[i0 + 1] = excl + v0;
        if (i0 + 1 < n) rowptr[i0 + 2] = excl + s1;
        if (i0 + 2 < n) rowptr[i0 + 3] = excl + s2;
        if (i0 + 3 < n) rowptr[i0 + 4] = excl + s3;
        carry += wsum[15];
        __syncthreads();
    }
}

__global__ __launch_bounds__(256)
void scatter_kernel(const int* __restrict__ srcA, const int* __restrict__ dstA,
                    const int* __restrict__ rowptr, int* __restrict__ cnt,
                    int* __restrict__ srcs, int E, int Et) {
    int e = blockIdx.x * blockDim.x + threadIdx.x;
    if (e >= Et) return;
    int s, d;
    if (e < E) { s = srcA[e]; d = dstA[e]; } else { s = e - E; d = s; }
    int pos = rowptr[d] + atomicAdd(&cnt[d], 1);
    srcs[pos] = s;
}

// ---------------- dual GEMM: outL(fp16) = X@Wl, outR(fp32) = X@Wr ------------
// 64 rows x 256 cols per block, K staged 32 at a time, 8x8 register tile.

__global__ __launch_bounds__(256)
void gemm_dual(const float* __restrict__ X, const float* __restrict__ Wl,
               const float* __restrict__ Wr, __half* __restrict__ outL,
               float* __restrict__ outR, int n) {
    __shared__ float sX[32][64];    // [k][row] transposed X tile
    __shared__ float sW[32][256];   // [k][col] cols 0-127 Wl, 128-255 Wr
    int tid  = threadIdx.x;
    int row0 = blockIdx.x * 64;
    int rowg = tid >> 5;            // 0..7  -> rows rowg*8..+7
    int colg = tid & 31;            // 0..31 -> cols colg*8..+7

    float acc[8][8] = {};

    for (int kt = 0; kt < 128; kt += 32) {
        // stage X tile: 64 rows x 32 k = 512 float4, coalesced
        #pragma unroll
        for (int i = 0; i < 2; ++i) {
            int id = i * 256 + tid;          // 0..511
            int r  = id >> 3;                // 0..63
            int kq = (id & 7) * 4;           // 0..28
            float4 xv = make_float4(0.f, 0.f, 0.f, 0.f);
            int gr = row0 + r;
            if (gr < n) xv = *(const float4*)(X + (size_t)gr * 128 + kt + kq);
            sX[kq + 0][r] = xv.x; sX[kq + 1][r] = xv.y;
            sX[kq + 2][r] = xv.z; sX[kq + 3][r] = xv.w;
        }
        // stage W tile: 32 k x 256 c = 2048 float4, coalesced
        #pragma unroll
        for (int i = 0; i < 8; ++i) {
            int id = i * 256 + tid;          // 0..2047
            int k  = id >> 6;                // 0..31
            int c  = (id & 63) * 4;          // 0..252
            const float* src = (c < 128)
                ? (Wl + (size_t)(kt + k) * 128 + c)
                : (Wr + (size_t)(kt + k) * 128 + (c - 128));
            *(float4*)&sW[k][c] = *(const float4*)src;
        }
        __syncthreads();
        #pragma unroll
        for (int k = 0; k < 32; ++k) {
            float xv8[8], wv8[8];
            *(float4*)&xv8[0] = *(const float4*)&sX[k][rowg * 8];
            *(float4*)&xv8[4] = *(const float4*)&sX[k][rowg * 8 + 4];
            *(float4*)&wv8[0] = *(const float4*)&sW[k][colg * 8];
            *(float4*)&wv8[4] = *(const float4*)&sW[k][colg * 8 + 4];
            #pragma unroll
            for (int r = 0; r < 8; ++r)
                #pragma unroll
                for (int c = 0; c < 8; ++c)
                    acc[r][c] += xv8[r] * wv8[c];
        }
        __syncthreads();
    }
    #pragma unroll
    for (int r = 0; r < 8; ++r) {
        int grow = row0 + rowg * 8 + r;
        if (grow >= n) break;
        if (colg < 16) {                      // fp16 xl output
            __half2 hh[4];
            #pragma unroll
            for (int c2 = 0; c2 < 4; ++c2)
                hh[c2] = __floats2half2_rn(acc[r][c2 * 2], acc[r][c2 * 2 + 1]);
            *(float4*)(outL + (size_t)grow * 128 + colg * 8) = *(float4*)&hh[0];
        } else {                              // fp32 xr output
            float* dst = outR + (size_t)grow * 128 + (colg - 16) * 8;
            *(float4*)(dst)     = *(float4*)&acc[r][0];
            *(float4*)(dst + 4) = *(float4*)&acc[r][4];
        }
    }
}

// ---------------- edge aggregation: one wave per dst node, online softmax ----
// GROUP = lanes per head group (16 for H=4/C=32, 64 for H=1/C=128)

template <int GROUP>
__global__ __launch_bounds__(256)
void edge_aggregate(const __half* __restrict__ xl, const float* __restrict__ xr,
                    const float* __restrict__ att, const float* __restrict__ bias,
                    const int* __restrict__ rowptr, const int* __restrict__ srcs,
                    float* __restrict__ out, int n, int relu_out) {
    int wave = blockIdx.x * (blockDim.x >> 6) + (threadIdx.x >> 6);
    int lane = threadIdx.x & 63;
    if (wave >= n) return;
    int ch = lane * 2;

    float2 xrv  = *(const float2*)(xr + (size_t)wave * 128 + ch);
    float2 attv = *(const float2*)(att + ch);

    float m = -INFINITY, l = 0.f, accx = 0.f, accy = 0.f;

#define DOTPRE(v, p) { \
        float ex = (v).x + xrv.x; ex = (ex > 0.f) ? ex : NEG_SLOPE * ex; \
        float ey = (v).y + xrv.y; ey = (ey > 0.f) ? ey : NEG_SLOPE * ey; \
        p = ex * attv.x + ey * attv.y; }

#define UPD(p, v) { \
        float mn = fmaxf(m, p); \
        float sc = __expf(m - mn); \
        float pe = __expf(p - mn); \
        accx = accx * sc + pe * (v).x; \
        accy = accy * sc + pe * (v).y; \
        l = l * sc + pe; m = mn; }

    int jb = rowptr[wave], je = rowptr[wave + 1];
    for (int base = jb; base < je; base += 64) {
        int idx  = base + lane;
        int myS  = (idx < je) ? srcs[idx] : 0;
        int cnt  = min(64, je - base);
        int t = 0;
        for (; t + 4 <= cnt; t += 4) {
            int s0 = __shfl(myS, t + 0, 64);
            int s1 = __shfl(myS, t + 1, 64);
            int s2 = __shfl(myS, t + 2, 64);
            int s3 = __shfl(myS, t + 3, 64);
            float2 v0 = __half22float2(*(const __half2*)(xl + (size_t)s0 * 128 + ch));
            float2 v1 = __half22float2(*(const __half2*)(xl + (size_t)s1 * 128 + ch));
            float2 v2 = __half22float2(*(const __half2*)(xl + (size_t)s2 * 128 + ch));
            float2 v3 = __half22float2(*(const __half2*)(xl + (size_t)s3 * 128 + ch));
            float p0, p1, p2, p3;
            DOTPRE(v0, p0); DOTPRE(v1, p1); DOTPRE(v2, p2); DOTPRE(v3, p3);
            #pragma unroll
            for (int off = 1; off < GROUP; off <<= 1) {
                p0 += __shfl_xor(p0, off, 64);
                p1 += __shfl_xor(p1, off, 64);
                p2 += __shfl_xor(p2, off, 64);
                p3 += __shfl_xor(p3, off, 64);
            }
            UPD(p0, v0); UPD(p1, v1); UPD(p2, v2); UPD(p3, v3);
        }
        for (; t < cnt; ++t) {
            int s = __shfl(myS, t, 64);
            float2 v = __half22float2(*(const __half2*)(xl + (size_t)s * 128 + ch));
            float p;
            DOTPRE(v, p);
            #pragma unroll
            for (int off = 1; off < GROUP; off <<= 1) p += __shfl_xor(p, off, 64);
            UPD(p, v);
        }
    }
#undef DOTPRE
#undef UPD

    float inv = 1.0f / l;            // every node has a self loop -> l > 0
    float2 bv = *(const float2*)(bias + ch);
    float ox = accx * inv + bv.x;
    float oy = accy * inv + bv.y;
    if (relu_out) { ox = fmaxf(ox, 0.f); oy = fmaxf(oy, 0.f); }
    *(float2*)(out + (size_t)wave * 128 + ch) = make_float2(ox, oy);
}

// ---------------- launch -----------------------------------------------------

extern "C" void kernel_launch(void* const* d_in, const int* in_sizes, int n_in,
                              void* d_out, int out_size, void* d_ws, size_t ws_size,
                              hipStream_t stream) {
    const float* x    = (const float*)d_in[0];
    const int*   ei   = (const int*)d_in[1];   // [2,E] int32
    const float* Wl1  = (const float*)d_in[2];
    const float* Wr1  = (const float*)d_in[3];
    const float* att1 = (const float*)d_in[4]; // [4,32] -> flat 128
    const float* b1   = (const float*)d_in[5];
    const float* Wl2  = (const float*)d_in[6];
    const float* Wr2  = (const float*)d_in[7];
    const float* att2 = (const float*)d_in[8]; // [1,128]
    const float* b2   = (const float*)d_in[9];

    int n  = in_sizes[0] / 128;
    int E  = in_sizes[1] / 2;
    int Et = E + n;                  // with self loops

    float* ws   = (float*)d_ws;
    float* xr   = ws;                              // [n,128] fp32
    float* h    = xr + (size_t)n * 128;            // [n,128] fp32
    __half* xlh = (__half*)(h + (size_t)n * 128);  // [n,128] fp16
    int* rowptr = (int*)(xlh + (size_t)n * 128);   // [n+1]
    int* cnt    = rowptr + (n + 1);                // [n] (also deg histogram)
    int* srcs   = cnt + n;                         // [Et]

    const int* srcA = ei;
    const int* dstA = ei + E;

    // CSR build (reused by both layers)
    hipMemsetAsync(cnt, 0, (size_t)n * 4, stream);
    hist_kernel<<<(Et + 255) / 256, 256, 0, stream>>>(dstA, cnt, E, Et);
    scan_block<<<1, 1024, 0, stream>>>(cnt, rowptr, n);
    hipMemsetAsync(cnt, 0, (size_t)n * 4, stream);
    scatter_kernel<<<(Et + 255) / 256, 256, 0, stream>>>(srcA, dstA, rowptr, cnt, srcs, E, Et);

    int gemm_grid = (n + 63) / 64;
    int edge_grid = (n + 3) / 4;

    // layer 1 (H=4, C=32): h = relu(aggregate + b1)
    gemm_dual<<<gemm_grid, 256, 0, stream>>>(x, Wl1, Wr1, xlh, xr, n);
    edge_aggregate<16><<<edge_grid, 256, 0, stream>>>(xlh, xr, att1, b1, rowptr, srcs, h, n, 1);

    // layer 2 (H=1, C=128): out = aggregate + b2
    gemm_dual<<<gemm_grid, 256, 0, stream>>>(h, Wl2, Wr2, xlh, xr, n);
    edge_aggregate<64><<<edge_grid, 256, 0, stream>>>(xlh, xr, att2, b2, rowptr, srcs, (float*)d_out, n, 0);
}

// Round 3
// 358.720 us; speedup vs baseline: 1.7109x; 1.3114x over previous
//
#include <hip/hip_runtime.h>
#include <hip/hip_fp16.h>
#include <math.h>

// ---------------------------------------------------------------------------
// GATv2 x2 layers, N=50000, D=128, HID=128, heads 4 then 1, E=800000 (+ self loops)
//   1) CSR build by dst (hist -> vectorized scan -> scatter), reused by both layers
//   2) fp16 MFMA dual GEMM: [xl|xr](fp16) = Xh @ [Wl|Wr]  (fp32 accumulate)
//   3) edge aggregation: one wave per dst node, online softmax, fp16 gathers,
//      4-edge ILP unroll, no float atomics
// ---------------------------------------------------------------------------

#define NEG_SLOPE 0.2f

typedef _Float16 half8 __attribute__((ext_vector_type(8)));
typedef _Float16 half4v __attribute__((ext_vector_type(4)));
typedef float floatx4 __attribute__((ext_vector_type(4)));

// ---------------- CSR build --------------------------------------------------

__global__ __launch_bounds__(256)
void hist_kernel(const int* __restrict__ dstA, int* __restrict__ deg, int E, int Et) {
    int e = blockIdx.x * blockDim.x + threadIdx.x;
    if (e >= Et) return;
    int d = (e < E) ? dstA[e] : (e - E);   // self loops appended after edges
    atomicAdd(&deg[d], 1);
}

// single-block exclusive scan producing rowptr[0..n], 4 elements/thread/iter
__global__ __launch_bounds__(1024)
void scan_block(const int* __restrict__ deg, int* __restrict__ rowptr, int n) {
    __shared__ int wsum[16];
    int t = threadIdx.x;
    int lane = t & 63, wid = t >> 6;
    int carry = 0;
    if (t == 0) rowptr[0] = 0;
    for (int base = 0; base < n; base += 4096) {
        int i0 = base + t * 4;
        int v0 = 0, v1 = 0, v2 = 0, v3 = 0;
        if (i0 + 3 < n) {
            int4 q = *(const int4*)(deg + i0);
            v0 = q.x; v1 = q.y; v2 = q.z; v3 = q.w;
        } else {
            if (i0 + 0 < n) v0 = deg[i0 + 0];
            if (i0 + 1 < n) v1 = deg[i0 + 1];
            if (i0 + 2 < n) v2 = deg[i0 + 2];
            if (i0 + 3 < n) v3 = deg[i0 + 3];
        }
        int s1 = v0 + v1, s2 = s1 + v2, s3 = s2 + v3;
        int x = s3;
        #pragma unroll
        for (int off = 1; off < 64; off <<= 1) {
            int y = __shfl_up(x, off, 64);
            if (lane >= off) x += y;
        }
        if (lane == 63) wsum[wid] = x;
        __syncthreads();
        if (wid == 0) {
            int s = (lane < 16) ? wsum[lane] : 0;
            #pragma unroll
            for (int off = 1; off < 16; off <<= 1) {
                int y = __shfl_up(s, off, 64);
                if (lane >= off) s += y;
            }
            if (lane < 16) wsum[lane] = s;
        }
        __syncthreads();
        int woff = (wid == 0) ? 0 : wsum[wid - 1];
        int excl = carry + woff + x - s3;      // exclusive prefix of this thread's 4
        if (i0 + 0 < n) rowptr[i0 + 1] = excl + v0;
        if (i0 + 1 < n) rowptr[i0 + 2] = excl + s1;
        if (i0 + 2 < n) rowptr[i0 + 3] = excl + s2;
        if (i0 + 3 < n) rowptr[i0 + 4] = excl + s3;
        carry += wsum[15];
        __syncthreads();
    }
}

__global__ __launch_bounds__(256)
void scatter_kernel(const int* __restrict__ srcA, const int* __restrict__ dstA,
                    const int* __restrict__ rowptr, int* __restrict__ cnt,
                    int* __restrict__ srcs, int E, int Et) {
    int e = blockIdx.x * blockDim.x + threadIdx.x;
    if (e >= Et) return;
    int s, d;
    if (e < E) { s = srcA[e]; d = dstA[e]; } else { s = e - E; d = s; }
    int pos = rowptr[d] + atomicAdd(&cnt[d], 1);
    srcs[pos] = s;
}

// ---------------- converts ---------------------------------------------------

__global__ __launch_bounds__(256)
void convert_x(const float* __restrict__ X, _Float16* __restrict__ Xh, int total4) {
    int id = blockIdx.x * blockDim.x + threadIdx.x;
    if (id >= total4) return;
    float4 v = *(const float4*)(X + (size_t)id * 4);
    half4v h;
    h[0] = (_Float16)v.x; h[1] = (_Float16)v.y;
    h[2] = (_Float16)v.z; h[3] = (_Float16)v.w;
    *(half4v*)(Xh + (size_t)id * 4) = h;
}

// Wt[c][k] = (c<128 ? Wl[k][c] : Wr[k][c-128]), fp16, c in [0,256)
__global__ __launch_bounds__(256)
void convert_w(const float* __restrict__ Wl, const float* __restrict__ Wr,
               _Float16* __restrict__ Wt) {
    int t = blockIdx.x * blockDim.x + threadIdx.x;   // 0..32767
    int c = t >> 7, k = t & 127;
    float v = (c < 128) ? Wl[(size_t)k * 128 + c] : Wr[(size_t)k * 128 + (c - 128)];
    Wt[(size_t)c * 128 + k] = (_Float16)v;
}

// ---------------- MFMA dual GEMM ---------------------------------------------
// C[n x 256] = A[n x 128] @ W[128 x 256]; cols 0-127 -> outL, 128-255 -> outR.
// Block: 64 rows x 256 cols, 4 waves (16 rows x 256 cols each).
// A frags straight from global (each wave owns its rows); Bt fully in LDS.
#define BPAD 136   // LDS row length in halves (128 + 8 pad -> conflict-free b128)

__global__ __launch_bounds__(256)
void gemm_mfma(const _Float16* __restrict__ A, const _Float16* __restrict__ Bt,
               _Float16* __restrict__ outL, _Float16* __restrict__ outR, int n) {
    __shared__ _Float16 sB[256 * BPAD];
    int tid = threadIdx.x;
    // stage Bt [256][128] -> LDS padded; wave covers 4 rows of 1KB, coalesced
    {
        int c0 = (tid & 15) * 8;
        int r0 = tid >> 4;
        #pragma unroll
        for (int i = 0; i < 16; ++i) {
            int r = r0 + i * 16;
            *(half8*)(sB + r * BPAD + c0) = *(const half8*)(Bt + (size_t)r * 128 + c0);
        }
    }
    int wave = tid >> 6;
    int lane = tid & 63;
    int ln = lane & 15;          // M/N index within 16-tile
    int q  = lane >> 4;          // k quad: k = q*8..q*8+7
    int row0 = blockIdx.x * 64 + wave * 16;

    int arow = row0 + ln;
    if (arow >= n) arow = n - 1;             // clamp; stores guarded below
    const _Float16* ap = A + (size_t)arow * 128 + q * 8;
    half8 a0 = *(const half8*)(ap);
    half8 a1 = *(const half8*)(ap + 32);
    half8 a2 = *(const half8*)(ap + 64);
    half8 a3 = *(const half8*)(ap + 96);

    __syncthreads();

    floatx4 acc[16];
    #pragma unroll
    for (int ct = 0; ct < 16; ++ct) {
        const _Float16* bp = sB + (ct * 16 + ln) * BPAD + q * 8;
        half8 b0 = *(const half8*)(bp);
        half8 b1 = *(const half8*)(bp + 32);
        half8 b2 = *(const half8*)(bp + 64);
        half8 b3 = *(const half8*)(bp + 96);
        floatx4 c = {0.f, 0.f, 0.f, 0.f};
        c = __builtin_amdgcn_mfma_f32_16x16x32_f16(a0, b0, c, 0, 0, 0);
        c = __builtin_amdgcn_mfma_f32_16x16x32_f16(a1, b1, c, 0, 0, 0);
        c = __builtin_amdgcn_mfma_f32_16x16x32_f16(a2, b2, c, 0, 0, 0);
        c = __builtin_amdgcn_mfma_f32_16x16x32_f16(a3, b3, c, 0, 0, 0);
        acc[ct] = c;
    }

    // epilogue: C/D layout col=lane&15, row=(lane>>4)*4+reg
    #pragma unroll
    for (int ct = 0; ct < 16; ++ct) {
        int col = ct * 16 + ln;
        #pragma unroll
        for (int r = 0; r < 4; ++r) {
            int grow = row0 + q * 4 + r;
            if (grow < n) {
                _Float16 v = (_Float16)acc[ct][r];
                if (ct < 8) outL[(size_t)grow * 128 + col] = v;
                else        outR[(size_t)grow * 128 + (col - 128)] = v;
            }
        }
    }
}

// ---------------- edge aggregation: one wave per dst node, online softmax ----
// GROUP = lanes per head group (16 for H=4/C=32, 64 for H=1/C=128)
// OUT_HALF: layer-1 writes fp16 h; layer-2 writes fp32 d_out.

template <int GROUP, bool OUT_HALF>
__global__ __launch_bounds__(256)
void edge_aggregate(const __half* __restrict__ xl, const __half* __restrict__ xr,
                    const float* __restrict__ att, const float* __restrict__ bias,
                    const int* __restrict__ rowptr, const int* __restrict__ srcs,
                    void* __restrict__ outv, int n, int relu_out) {
    int wave = blockIdx.x * (blockDim.x >> 6) + (threadIdx.x >> 6);
    int lane = threadIdx.x & 63;
    if (wave >= n) return;
    int ch = lane * 2;

    float2 xrv  = __half22float2(*(const __half2*)(xr + (size_t)wave * 128 + ch));
    float2 attv = *(const float2*)(att + ch);

    float m = -INFINITY, l = 0.f, accx = 0.f, accy = 0.f;

#define DOTPRE(v, p) { \
        float ex = (v).x + xrv.x; ex = (ex > 0.f) ? ex : NEG_SLOPE * ex; \
        float ey = (v).y + xrv.y; ey = (ey > 0.f) ? ey : NEG_SLOPE * ey; \
        p = ex * attv.x + ey * attv.y; }

#define UPD(p, v) { \
        float mn = fmaxf(m, p); \
        float sc = __expf(m - mn); \
        float pe = __expf(p - mn); \
        accx = accx * sc + pe * (v).x; \
        accy = accy * sc + pe * (v).y; \
        l = l * sc + pe; m = mn; }

    int jb = rowptr[wave], je = rowptr[wave + 1];
    for (int base = jb; base < je; base += 64) {
        int idx  = base + lane;
        int myS  = (idx < je) ? srcs[idx] : 0;
        int cnt  = min(64, je - base);
        int t = 0;
        for (; t + 4 <= cnt; t += 4) {
            int s0 = __shfl(myS, t + 0, 64);
            int s1 = __shfl(myS, t + 1, 64);
            int s2 = __shfl(myS, t + 2, 64);
            int s3 = __shfl(myS, t + 3, 64);
            float2 v0 = __half22float2(*(const __half2*)(xl + (size_t)s0 * 128 + ch));
            float2 v1 = __half22float2(*(const __half2*)(xl + (size_t)s1 * 128 + ch));
            float2 v2 = __half22float2(*(const __half2*)(xl + (size_t)s2 * 128 + ch));
            float2 v3 = __half22float2(*(const __half2*)(xl + (size_t)s3 * 128 + ch));
            float p0, p1, p2, p3;
            DOTPRE(v0, p0); DOTPRE(v1, p1); DOTPRE(v2, p2); DOTPRE(v3, p3);
            #pragma unroll
            for (int off = 1; off < GROUP; off <<= 1) {
                p0 += __shfl_xor(p0, off, 64);
                p1 += __shfl_xor(p1, off, 64);
                p2 += __shfl_xor(p2, off, 64);
                p3 += __shfl_xor(p3, off, 64);
            }
            UPD(p0, v0); UPD(p1, v1); UPD(p2, v2); UPD(p3, v3);
        }
        for (; t < cnt; ++t) {
            int s = __shfl(myS, t, 64);
            float2 v = __half22float2(*(const __half2*)(xl + (size_t)s * 128 + ch));
            float p;
            DOTPRE(v, p);
            #pragma unroll
            for (int off = 1; off < GROUP; off <<= 1) p += __shfl_xor(p, off, 64);
            UPD(p, v);
        }
    }
#undef DOTPRE
#undef UPD

    float inv = 1.0f / l;            // every node has a self loop -> l > 0
    float2 bv = *(const float2*)(bias + ch);
    float ox = accx * inv + bv.x;
    float oy = accy * inv + bv.y;
    if (relu_out) { ox = fmaxf(ox, 0.f); oy = fmaxf(oy, 0.f); }
    if (OUT_HALF) {
        __half* out = (__half*)outv;
        *(__half2*)(out + (size_t)wave * 128 + ch) = __floats2half2_rn(ox, oy);
    } else {
        float* out = (float*)outv;
        *(float2*)(out + (size_t)wave * 128 + ch) = make_float2(ox, oy);
    }
}

// ---------------- launch -----------------------------------------------------

extern "C" void kernel_launch(void* const* d_in, const int* in_sizes, int n_in,
                              void* d_out, int out_size, void* d_ws, size_t ws_size,
                              hipStream_t stream) {
    const float* x    = (const float*)d_in[0];
    const int*   ei   = (const int*)d_in[1];   // [2,E] int32
    const float* Wl1  = (const float*)d_in[2];
    const float* Wr1  = (const float*)d_in[3];
    const float* att1 = (const float*)d_in[4]; // [4,32] -> flat 128
    const float* b1   = (const float*)d_in[5];
    const float* Wl2  = (const float*)d_in[6];
    const float* Wr2  = (const float*)d_in[7];
    const float* att2 = (const float*)d_in[8]; // [1,128]
    const float* b2   = (const float*)d_in[9];

    int n  = in_sizes[0] / 128;
    int E  = in_sizes[1] / 2;
    int Et = E + n;                  // with self loops

    _Float16* xlh = (_Float16*)d_ws;               // [n,128]
    _Float16* xrh = xlh + (size_t)n * 128;         // [n,128]
    _Float16* hh  = xrh + (size_t)n * 128;         // [n,128]
    _Float16* Xh  = hh  + (size_t)n * 128;         // [n,128]
    _Float16* Wt1 = Xh  + (size_t)n * 128;         // [256,128]
    _Float16* Wt2 = Wt1 + 256 * 128;               // [256,128]
    int* rowptr = (int*)(Wt2 + 256 * 128);         // [n+1]
    int* cnt    = rowptr + (n + 1);                // [n] (also deg histogram)
    int* srcs   = cnt + n;                         // [Et]

    const int* srcA = ei;
    const int* dstA = ei + E;

    // CSR build (reused by both layers)
    hipMemsetAsync(cnt, 0, (size_t)n * 4, stream);
    hist_kernel<<<(Et + 255) / 256, 256, 0, stream>>>(dstA, cnt, E, Et);
    scan_block<<<1, 1024, 0, stream>>>(cnt, rowptr, n);
    hipMemsetAsync(cnt, 0, (size_t)n * 4, stream);
    scatter_kernel<<<(Et + 255) / 256, 256, 0, stream>>>(srcA, dstA, rowptr, cnt, srcs, E, Et);

    // converts
    int total4 = n * 128 / 4;
    convert_x<<<(total4 + 255) / 256, 256, 0, stream>>>(x, Xh, total4);
    convert_w<<<128, 256, 0, stream>>>(Wl1, Wr1, Wt1);
    convert_w<<<128, 256, 0, stream>>>(Wl2, Wr2, Wt2);

    int gemm_grid = (n + 63) / 64;
    int edge_grid = (n + 3) / 4;

    // layer 1 (H=4, C=32): h = relu(aggregate + b1), fp16
    gemm_mfma<<<gemm_grid, 256, 0, stream>>>(Xh, Wt1, xlh, xrh, n);
    edge_aggregate<16, true><<<edge_grid, 256, 0, stream>>>(
        (const __half*)xlh, (const __half*)xrh, att1, b1, rowptr, srcs, hh, n, 1);

    // layer 2 (H=1, C=128): out = aggregate + b2, fp32
    gemm_mfma<<<gemm_grid, 256, 0, stream>>>(hh, Wt2, xlh, xrh, n);
    edge_aggregate<64, false><<<edge_grid, 256, 0, stream>>>(
        (const __half*)xlh, (const __half*)xrh, att2, b2, rowptr, srcs, d_out, n, 0);
}